// Round 1
// baseline (63697.180 us; speedup 1.0000x reference)
//
#include <hip/hip_runtime.h>
#include <math.h>

#define TSTEPS 1024
#define NXD 128
#define NAD 64
#define NBLK 64
#define LSTR 67      // LDS row stride (conflict-free for stride-67 col reads)
#define GAINW 129

// ---------- lane-broadcast helpers ----------
__device__ __forceinline__ float rdl(float v, int l) {
  return __int_as_float(__builtin_amdgcn_readlane(__float_as_int(v), l));
}
__device__ __forceinline__ double rdl(double v, int l) {
  unsigned long long b = (unsigned long long)__double_as_longlong(v);
  int lo = __builtin_amdgcn_readlane((int)(b & 0xffffffffULL), l);
  int hi = __builtin_amdgcn_readlane((int)(b >> 32), l);
  unsigned long long r = (((unsigned long long)(unsigned)hi) << 32) | (unsigned)lo;
  return __longlong_as_double((long long)r);
}

// ---------- device-wide barrier (cumulative-count, agent scope) ----------
__device__ __forceinline__ void gbar(unsigned* arrive, unsigned* epoch, unsigned e) {
  __syncthreads();
  if (threadIdx.x == 0) {
    unsigned prev = __hip_atomic_fetch_add(arrive, 1u, __ATOMIC_ACQ_REL, __HIP_MEMORY_SCOPE_AGENT);
    if (prev == e * NBLK - 1u) {
      __hip_atomic_store(epoch, e, __ATOMIC_RELEASE, __HIP_MEMORY_SCOPE_AGENT);
    } else {
      while (__hip_atomic_load(epoch, __ATOMIC_ACQUIRE, __HIP_MEMORY_SCOPE_AGENT) < e) {
        __builtin_amdgcn_s_sleep(1);
      }
    }
  }
  __syncthreads();
}

// ---------- unpivoted LDL^T factor, lane = row, in registers ----------
// Stored matrix rows are QaaC rows (== Qaa columns; Qaa is symmetric to ~1e-6).
// Returns wave-max multiplier magnitude (growth monitor).
__device__ __forceinline__ float factor32(const float* __restrict__ QaaC, int lane,
                                          float* __restrict__ Lsh) {
  float a[64];
#pragma unroll
  for (int k = 0; k < 64; ++k) a[k] = QaaC[lane * NAD + k];
  float mmax = 0.f;
#pragma unroll
  for (int j = 0; j < 63; ++j) {
    float d = rdl(a[j], j);
    d = (d == 0.f) ? 1e-30f : d;
    float rdv = 1.0f / d;
    float m = a[j] * rdv;
    m = (lane > j) ? m : 0.f;          // inactive lanes contribute 0
    mmax = fmaxf(mmax, fabsf(m));
#pragma unroll
    for (int k = j + 1; k < 64; ++k) {
      float u = rdl(a[j], k);          // = A[k][j] == A[j][k] (symmetric trick)
      a[k] = fmaf(-m, u, a[k]);
    }
    if (lane > j) a[j] = m;            // store multiplier (L), keep D on diagonal lane
  }
#pragma unroll
  for (int k = 0; k < 64; ++k) Lsh[lane * LSTR + k] = a[k];
#pragma unroll
  for (int s = 1; s < 64; s <<= 1) mmax = fmaxf(mmax, __shfl_xor(mmax, s));
  return mmax;
}

__device__ __forceinline__ void factor64(const float* __restrict__ QaaC, int lane,
                                         double* __restrict__ Lsh) {
  double a[64];
#pragma unroll
  for (int k = 0; k < 64; ++k) a[k] = (double)QaaC[lane * NAD + k];
#pragma unroll
  for (int j = 0; j < 63; ++j) {
    double d = rdl(a[j], j);
    d = (d == 0.0) ? 1e-300 : d;
    double rdv = 1.0 / d;
    double m = a[j] * rdv;
    m = (lane > j) ? m : 0.0;
#pragma unroll
    for (int k = j + 1; k < 64; ++k) {
      double u = rdl(a[j], k);
      a[k] = fma(-m, u, a[k]);
    }
    if (lane > j) a[j] = m;
  }
#pragma unroll
  for (int k = 0; k < 64; ++k) Lsh[lane * LSTR + k] = a[k];
}

// ---------- triangular solve (one RHS per wave, lane = row) ----------
template <typename T>
__device__ __forceinline__ void trisolve(const T* __restrict__ Lsh, int lane, float bval,
                                         float* __restrict__ gout, float* __restrict__ kout) {
  T x = (T)bval;
  for (int j = 0; j < 63; ++j) {       // forward: L y = b (unit diag)
    T xj = rdl(x, j);
    T lij = Lsh[lane * LSTR + j];
    if (lane > j) x = x - lij * xj;
  }
  T d = Lsh[lane * LSTR + lane];
  if (d == (T)0) d = (T)1e-30;
  x = x / d;                           // D z = y
  for (int j = 63; j > 0; --j) {       // backward: L^T w = z
    T xj = rdl(x, j);
    T lji = Lsh[j * LSTR + lane];
    if (lane < j) x = x - lji * xj;
  }
  float g = -(float)x;                 // gains = -Qaa^{-1} rhs
  *gout = g;
  *kout = g;
}

// ---------- w = Vxx @ col (Vxx symmetric -> read rows as columns) ----------
// lane owns output rows {2*lane, 2*lane+1}; fcl/fch hold col[lane], col[64+lane].
__device__ __forceinline__ void matvec128(const float* __restrict__ Vxx, float fcl, float fch,
                                          int lane, float& w0, float& w1) {
  w0 = 0.f; w1 = 0.f;
  const float* vrow = Vxx + 2 * lane;
#pragma unroll 8
  for (int c = 0; c < 64; ++c) {
    float s = rdl(fcl, c);
    float2 v = *(const float2*)(vrow + (size_t)c * NXD);
    w0 = fmaf(v.x, s, w0); w1 = fmaf(v.y, s, w1);
  }
#pragma unroll 8
  for (int c = 0; c < 64; ++c) {
    float s = rdl(fch, c);
    float2 v = *(const float2*)(vrow + (size_t)(64 + c) * NXD);
    w0 = fmaf(v.x, s, w0); w1 = fmaf(v.y, s, w1);
  }
}

__global__ void init_bar_kernel(unsigned* bar) {
  bar[threadIdx.x] = 0u;
}

__global__ __launch_bounds__(256, 1) void ilqr_main(
    const float* __restrict__ fx, const float* __restrict__ fa,
    const float* __restrict__ lx, const float* __restrict__ la,
    const float* __restrict__ lxx, const float* __restrict__ laa,
    const float* __restrict__ lax, float* __restrict__ out,
    float* __restrict__ wsf, unsigned* __restrict__ bar) {

  __shared__ float  LfS[64 * LSTR];
  __shared__ double LdS[64 * LSTR];
  __shared__ int flag64;

  const int b = blockIdx.x;
  const int tid = threadIdx.x;
  const int wave = tid >> 6;
  const int lane = tid & 63;

  // workspace layout (floats)
  float* Vxx  = wsf;               // 128*128, kept exactly symmetric
  float* Vx   = Vxx + 16384;       // 128
  float* QxxC = Vx + 128;          // 128*128, QxxC[j][i] = Qxx[i][j]
  float* QaxT = QxxC + 16384;      // 128*64,  QaxT[x][a] = Qax[a][x]
  float* QaaC = QaxT + 8192;       // 64*64,   QaaC[j][a] = Qaa[a][j]
  float* Qx   = QaaC + 4096;       // 128
  float* Qa   = Qx + 128;          // 64
  float* KT   = Qa + 64;           // 129*64, KT[m][a] = gains col m

  unsigned* arrive = bar;
  unsigned* epoch  = bar + 32;
  unsigned ep = 0;

  // ---- init carry: Vxx = lxx[T-1], Vx = lx[T-1] ----
  {
    const float* src = lxx + (size_t)(TSTEPS - 1) * NXD * NXD;
    int idx = b * 256 + tid;
    if (idx < NXD * NXD) Vxx[idx] = src[idx];
    if (b == 0 && tid < NXD) Vx[tid] = lx[(size_t)(TSTEPS - 1) * NXD + tid];
  }
  ++ep; gbar(arrive, epoch, ep);

  for (int t = TSTEPS - 1; t >= 0; --t) {
    const float* fxt  = fx  + (size_t)t * NXD * NXD;
    const float* fat  = fa  + (size_t)t * NXD * NAD;
    const float* lxt  = lx  + (size_t)t * NXD;
    const float* lat  = la  + (size_t)t * NAD;
    const float* lxxt = lxx + (size_t)t * NXD * NXD;
    const float* laat = laa + (size_t)t * NAD * NAD;
    const float* laxt = lax + (size_t)t * NAD * NXD;

    // ================= PHASE 1: assemble Qxx, Qax, Qaa, Qx, Qa =================
    if (wave <= 1) {
      const int j = 2 * b + wave;  // fx column index
      float fcl = fxt[lane * NXD + j];
      float fch = fxt[(64 + lane) * NXD + j];
      float w0, w1;
      matvec128(Vxx, fcl, fch, lane, w0, w1);   // w = Vxx @ fx[:,j]

      float q0 = lxxt[(size_t)(2 * lane) * NXD + j];
      float q1 = lxxt[(size_t)(2 * lane + 1) * NXD + j];
      float qa = laxt[lane * NXD + j];
#pragma unroll 4
      for (int r2 = 0; r2 < 32; ++r2) {
        float s0 = rdl(w0, r2), s1 = rdl(w1, r2);          // w[2r2], w[2r2+1]
        float t0 = s0 + rdl(fcl, 2 * r2);                  // (Vxx+I)@col
        float t1 = s1 + rdl(fcl, 2 * r2 + 1);
        float2 f0 = *(const float2*)(fxt + (size_t)(2 * r2) * NXD + 2 * lane);
        float2 f1 = *(const float2*)(fxt + (size_t)(2 * r2 + 1) * NXD + 2 * lane);
        float g0 = fat[(2 * r2) * NAD + lane];
        float g1 = fat[(2 * r2 + 1) * NAD + lane];
        q0 = fmaf(f0.x, s0, q0); q1 = fmaf(f0.y, s0, q1);
        q0 = fmaf(f1.x, s1, q0); q1 = fmaf(f1.y, s1, q1);
        qa = fmaf(g0, t0, qa);   qa = fmaf(g1, t1, qa);
      }
#pragma unroll 4
      for (int r2 = 32; r2 < 64; ++r2) {
        float s0 = rdl(w0, r2), s1 = rdl(w1, r2);
        float t0 = s0 + rdl(fch, 2 * r2 - 64);
        float t1 = s1 + rdl(fch, 2 * r2 + 1 - 64);
        float2 f0 = *(const float2*)(fxt + (size_t)(2 * r2) * NXD + 2 * lane);
        float2 f1 = *(const float2*)(fxt + (size_t)(2 * r2 + 1) * NXD + 2 * lane);
        float g0 = fat[(2 * r2) * NAD + lane];
        float g1 = fat[(2 * r2 + 1) * NAD + lane];
        q0 = fmaf(f0.x, s0, q0); q1 = fmaf(f0.y, s0, q1);
        q0 = fmaf(f1.x, s1, q0); q1 = fmaf(f1.y, s1, q1);
        qa = fmaf(g0, t0, qa);   qa = fmaf(g1, t1, qa);
      }
      *(float2*)(QxxC + (size_t)j * NXD + 2 * lane) = make_float2(q0, q1);
      QaxT[j * NAD + lane] = qa;
    } else if (wave == 2) {
      const int j = b;             // fa column index
      float fcl = fat[lane * NAD + j];
      float fch = fat[(64 + lane) * NAD + j];
      float w0, w1;
      matvec128(Vxx, fcl, fch, lane, w0, w1);   // w = Vxx @ fa[:,j]

      float qa = laat[lane * NAD + j];
#pragma unroll 4
      for (int r2 = 0; r2 < 32; ++r2) {
        float t0 = rdl(w0, r2) + rdl(fcl, 2 * r2);
        float t1 = rdl(w1, r2) + rdl(fcl, 2 * r2 + 1);
        float g0 = fat[(2 * r2) * NAD + lane];
        float g1 = fat[(2 * r2 + 1) * NAD + lane];
        qa = fmaf(g0, t0, qa); qa = fmaf(g1, t1, qa);
      }
#pragma unroll 4
      for (int r2 = 32; r2 < 64; ++r2) {
        float t0 = rdl(w0, r2) + rdl(fch, 2 * r2 - 64);
        float t1 = rdl(w1, r2) + rdl(fch, 2 * r2 + 1 - 64);
        float g0 = fat[(2 * r2) * NAD + lane];
        float g1 = fat[(2 * r2 + 1) * NAD + lane];
        qa = fmaf(g0, t0, qa); qa = fmaf(g1, t1, qa);
      }
      QaaC[j * NAD + lane] = qa;
    } else {
      // Qx / Qa rows (stacked 192 rows across 64 blocks)
#pragma unroll
      for (int q = 0; q < 3; ++q) {
        int rr = 3 * b + q;
        float p;
        if (rr < NXD) {
          p = fxt[lane * NXD + rr] * Vx[lane] + fxt[(64 + lane) * NXD + rr] * Vx[64 + lane];
        } else {
          int aa = rr - NXD;
          p = fat[lane * NAD + aa] * Vx[lane] + fat[(64 + lane) * NAD + aa] * Vx[64 + lane];
        }
#pragma unroll
        for (int s = 1; s < 64; s <<= 1) p += __shfl_xor(p, s);
        if (lane == 0) {
          if (rr < NXD) Qx[rr] = lxt[rr] + p;
          else          Qa[rr - NXD] = lat[rr - NXD] + p;
        }
      }
    }
    ++ep; gbar(arrive, epoch, ep);

    // ================= PHASE 2: factor Qaa (redundant per block) + trisolve =================
    if (wave == 0) {
      float mmax = factor32(QaaC, lane, LfS);
      if (lane == 0) flag64 = !(mmax <= 64.0f);   // catches NaN too
    }
    __syncthreads();
    if (flag64) { if (wave == 0) factor64(QaaC, lane, LdS); }
    __syncthreads();
    {
      int m = (wave == 0) ? 2 * b
            : (wave == 1) ? 2 * b + 1
            : (wave == 2 && b == 0) ? 128 : -1;
      if (m >= 0) {
        float bval = (m == 0) ? Qa[lane] : QaxT[(size_t)(m - 1) * NAD + lane];
        float* gout = out + (size_t)t * NAD * GAINW + (size_t)lane * GAINW + m;
        float* kout = KT + m * NAD + lane;
        if (!flag64) trisolve<float >(LfS, lane, bval, gout, kout);
        else         trisolve<double>(LdS, lane, bval, gout, kout);
      }
    }
    ++ep; gbar(arrive, epoch, ep);

    // ================= PHASE 3: Vxx_n = sym(Qxx) + sym(Qax^T K); Vx_n = Qx + Qax^T k ======
    {
      int ti = b >> 3, tj = b & 7;
      int il = tid >> 4, jl = tid & 15;
      int i = ti * 16 + il, j = tj * 16 + jl;
      float d1 = 0.f, d2 = 0.f;
      const float* qi = QaxT + (size_t)i * NAD;
      const float* qj = QaxT + (size_t)j * NAD;
      const float* kj = KT + (size_t)(1 + j) * NAD;
      const float* ki = KT + (size_t)(1 + i) * NAD;
#pragma unroll 4
      for (int a4 = 0; a4 < 16; ++a4) {
        float4 A = *(const float4*)(qi + 4 * a4);
        float4 B = *(const float4*)(kj + 4 * a4);
        float4 C = *(const float4*)(qj + 4 * a4);
        float4 D = *(const float4*)(ki + 4 * a4);
        d1 = fmaf(A.x, B.x, d1); d1 = fmaf(A.y, B.y, d1);
        d1 = fmaf(A.z, B.z, d1); d1 = fmaf(A.w, B.w, d1);
        d2 = fmaf(C.x, D.x, d2); d2 = fmaf(C.y, D.y, d2);
        d2 = fmaf(C.z, D.z, d2); d2 = fmaf(C.w, D.w, d2);
      }
      // commutative adds -> block (tj,ti) writes the bitwise-identical value at (j,i)
      float v = 0.5f * (QxxC[(size_t)j * NXD + i] + QxxC[(size_t)i * NXD + j])
              + 0.5f * (d1 + d2);
      Vxx[(size_t)i * NXD + j] = v;

      if (ti == tj && jl == 0) {          // 8 diagonal blocks cover all 128 rows of Vx
        float acc = 0.f;
        const float* k0 = KT;             // KT[0] = k
#pragma unroll 4
        for (int a4 = 0; a4 < 16; ++a4) {
          float4 A = *(const float4*)(qi + 4 * a4);
          float4 B = *(const float4*)(k0 + 4 * a4);
          acc = fmaf(A.x, B.x, acc); acc = fmaf(A.y, B.y, acc);
          acc = fmaf(A.z, B.z, acc); acc = fmaf(A.w, B.w, acc);
        }
        Vx[i] = Qx[i] + acc;
      }
    }
    ++ep; gbar(arrive, epoch, ep);
  }
}

extern "C" void kernel_launch(void* const* d_in, const int* in_sizes, int n_in,
                              void* d_out, int out_size, void* d_ws, size_t ws_size,
                              hipStream_t stream) {
  const float* fx  = (const float*)d_in[0];
  const float* fa  = (const float*)d_in[1];
  const float* lx  = (const float*)d_in[2];
  const float* la  = (const float*)d_in[3];
  const float* lxx = (const float*)d_in[4];
  const float* laa = (const float*)d_in[5];
  const float* lax = (const float*)d_in[6];
  float* out = (float*)d_out;

  unsigned* bar = (unsigned*)d_ws;                  // 64 words, re-zeroed each call
  float* wsf = (float*)((char*)d_ws + 256);

  hipLaunchKernelGGL(init_bar_kernel, dim3(1), dim3(64), 0, stream, bar);
  hipLaunchKernelGGL(ilqr_main, dim3(NBLK), dim3(256), 0, stream,
                     fx, fa, lx, la, lxx, laa, lax, out, wsf, bar);
}